// Round 10
// baseline (328.265 us; speedup 1.0000x reference)
//
#include <hip/hip_runtime.h>

#define DEVINL __device__ __forceinline__

static constexpr int BLK = 256;

DEVINL float sigmoidf_(float x) { return 1.0f / (1.0f + __expf(-x)); }
// stable tanh: large +x -> exp=inf -> 1-0 = 1; large -x -> exp=0 -> 1-2 = -1
DEVINL float tanh_fast(float x) { return 1.0f - 2.0f / (__expf(2.0f * x) + 1.0f); }

DEVINL float dot44(float4 w, float4 h) {
  return w.x * h.x + w.y * h.y + w.z * h.z + w.w * h.w;
}

// ---- bf16 pack/unpack (RNE; finite values only) ----
DEVINL unsigned bfr_(float f) {
  unsigned u = __float_as_uint(f);
  return (u + 0x7fffu + ((u >> 16) & 1u)) >> 16;
}
DEVINL unsigned pk_bf16(float a, float b) { return bfr_(a) | (bfr_(b) << 16); }
DEVINL float blo_(unsigned u) { return __uint_as_float(u << 16); }
DEVINL float bhi_(unsigned u) { return __uint_as_float(u & 0xffff0000u); }
DEVINL void fma8(float* a, uint4 v, float w) {
  a[0] += w * blo_(v.x); a[1] += w * bhi_(v.x);
  a[2] += w * blo_(v.y); a[3] += w * bhi_(v.y);
  a[4] += w * blo_(v.z); a[5] += w * bhi_(v.z);
  a[6] += w * blo_(v.w); a[7] += w * bhi_(v.w);
}

// fused: zero deg/cnt + row-normalize feat -> featn and buf0 cols [0,8)
__global__ void prep_kernel(const float* __restrict__ feat, float* __restrict__ featn,
                            float* __restrict__ buf0, float* __restrict__ deg,
                            int* __restrict__ cnt, int N) {
  int n = blockIdx.x * blockDim.x + threadIdx.x;
  if (n >= N) return;
  deg[n] = 0.0f;
  cnt[n] = 0;
  const float4* fp = (const float4*)(feat + (size_t)n * 8);
  float4 a = fp[0], b = fp[1];
  float s = a.x + a.y + a.z + a.w + b.x + b.y + b.z + b.w;
  float r = 1.0f / s;
  a.x *= r; a.y *= r; a.z *= r; a.w *= r;
  b.x *= r; b.y *= r; b.z *= r; b.w *= r;
  float4* on = (float4*)(featn + (size_t)n * 8);
  on[0] = a; on[1] = b;
  float4* o0 = (float4*)(buf0 + (size_t)n * 24);
  o0[0] = a; o0[1] = b;
}

// Fused LSTM + edge pass, 4:1 block interleave (atomic-latency edge waves hide
// under VALU-bound LSTM waves). LSTM: 16 lanes/node, lane j owns h[j],c[j].
// W_hh lives in LDS (padded stride 20 -> only 2-way bank aliasing = free);
// W_ih + bias stay in registers (36 VGPRs). Round-8's all-register version
// needed 96 weight VGPRs but the compiler allocated 76 total and sank 120 L1
// loads into the unrolled loop (serial latency, 85us).
__global__ __launch_bounds__(256, 2) void lstm_edge_kernel(
    const float* __restrict__ featn,
    const float* __restrict__ W_ih, const float* __restrict__ W_hh,
    const float* __restrict__ b_ih, const float* __restrict__ b_hh,
    float* __restrict__ buf0, int N,
    const int* __restrict__ src, const int* __restrict__ dst,
    const float* __restrict__ ew, float* __restrict__ deg,
    int* __restrict__ cnt, int* __restrict__ pos, int E) {
  __shared__ float sWhh[64 * 20];  // [64 rows][16 used + 4 pad]
  __shared__ float hlds[256];
  const int b = blockIdx.x;
  const int g = b / 5, r = b - g * 5;
  if (r < 4) {
    // ---- LSTM branch ----
    for (int i = threadIdx.x; i < 1024; i += 256)
      sWhh[(i >> 4) * 20 + (i & 15)] = W_hh[i];
    __syncthreads();  // block-uniform branch: legal

    const int tid = (g * 4 + r) * 256 + (int)threadIdx.x;
    int node = tid >> 4;
    const bool store = node < N;
    if (node >= N) node = N - 1;  // clamp: keep wave shape, skip store
    const int j = tid & 15;

    float4 wia[4], wib[4];
    float bias[4];
#pragma unroll
    for (int gg = 0; gg < 4; ++gg) {
      const int row = 16 * gg + j;
      const float4* wi = (const float4*)(W_ih + row * 8);
      wia[gg] = wi[0]; wib[gg] = wi[1];
      bias[gg] = b_ih[row] + b_hh[row];
    }
    const float* grp = &hlds[threadIdx.x & ~15];

    float h = 0.0f, c = 0.0f;
    const int start = (node >= 5) ? (node - 5) : 0;
    const int nvalid = (node < 5) ? node : 5;
#pragma unroll
    for (int t = 0; t < 5; ++t) {
      float4 x0, x1;
      if (t < nvalid) {
        const float4* xr = (const float4*)(featn + (size_t)(start + t) * 8);
        x0 = xr[0]; x1 = xr[1];
      } else {
        x0 = make_float4(0.f, 0.f, 0.f, 0.f);
        x1 = x0;
      }
      hlds[threadIdx.x] = h;
      // wave-lockstep: all 16 lanes of the group wrote before any reads issue
      float4 hb0 = ((const float4*)grp)[0];
      float4 hb1 = ((const float4*)grp)[1];
      float4 hb2 = ((const float4*)grp)[2];
      float4 hb3 = ((const float4*)grp)[3];
      float gv[4];
#pragma unroll
      for (int gg = 0; gg < 4; ++gg) {
        const int row = 16 * gg + j;
        const float4* wh = (const float4*)&sWhh[row * 20];
        float acc = bias[gg] + dot44(wia[gg], x0) + dot44(wib[gg], x1);
        acc += dot44(wh[0], hb0) + dot44(wh[1], hb1)
             + dot44(wh[2], hb2) + dot44(wh[3], hb3);
        gv[gg] = acc;
      }
      const float ig = sigmoidf_(gv[0]);
      const float fg = sigmoidf_(gv[1]);
      const float gg2 = tanh_fast(gv[2]);
      const float og = sigmoidf_(gv[3]);
      c = fg * c + ig * gg2;
      h = og * tanh_fast(c);
    }
    if (store) buf0[(size_t)node * 24 + 8 + j] = h;
  } else {
    // ---- edge branch: 1024 consecutive edges per block, 4 per thread ----
    const int base = g * 1024 + (int)threadIdx.x;
    const int lane = threadIdx.x & 63;
    int dv[4], sv[4];
    float wv[4];
    bool v[4];
#pragma unroll
    for (int k = 0; k < 4; ++k) {
      const int e = base + k * 256;
      v[k] = e < E;
      dv[k] = v[k] ? dst[e] : 0;
      sv[k] = v[k] ? src[e] : -1;
      wv[k] = v[k] ? ew[e] : 0.0f;
    }
    int p[4];
#pragma unroll
    for (int k = 0; k < 4; ++k)
      if (v[k]) p[k] = atomicAdd(&cnt[dv[k]], 1);
    // deg segmented reduction (VALU/shfl) overlaps the atomic round-trips
#pragma unroll
    for (int k = 0; k < 4; ++k) {
      int s = sv[k];
      float acc = wv[k];
      int sprev = __shfl_up(s, 1, 64);
      unsigned f = (lane == 0 || sprev != s) ? 1u : 0u;
#pragma unroll
      for (int d = 1; d < 64; d <<= 1) {
        float o = __shfl_up(acc, d, 64);
        unsigned fo = __shfl_up(f, d, 64);
        if (lane >= d) {
          if (!f) acc += o;
          f |= fo;
        }
      }
      int snext = __shfl_down(s, 1, 64);
      bool tail = (lane == 63) || (snext != s);
      if (v[k] && tail && s >= 0) atomicAdd(&deg[s], acc);
    }
#pragma unroll
    for (int k = 0; k < 4; ++k)
      if (v[k]) pos[base + k * 256] = p[k];
  }
}

// ---- 3-stage parallel exclusive scan of cnt[N] -> rowptr[N+1] ----
__global__ void scan_block_kernel(const int* __restrict__ cnt, int* __restrict__ rowptr,
                                  int* __restrict__ blocksum, int N) {
  __shared__ int sd[256];
  const int t = threadIdx.x;
  const int base = blockIdx.x * 1024 + t * 4;
  int c0 = 0, c1 = 0, c2 = 0, c3 = 0;
  if (base + 3 < N) {
    int4 v = *(const int4*)(cnt + base);
    c0 = v.x; c1 = v.y; c2 = v.z; c3 = v.w;
  } else {
    if (base < N) c0 = cnt[base];
    if (base + 1 < N) c1 = cnt[base + 1];
    if (base + 2 < N) c2 = cnt[base + 2];
  }
  int s = c0 + c1 + c2 + c3;
  sd[t] = s;
  __syncthreads();
  for (int d = 1; d < 256; d <<= 1) {
    int v = (t >= d) ? sd[t - d] : 0;
    __syncthreads();
    sd[t] += v;
    __syncthreads();
  }
  if (t == 255) blocksum[blockIdx.x] = sd[255];
  int p = sd[t] - s;  // exclusive
  if (base < N)     { rowptr[base] = p;     p += c0; }
  if (base + 1 < N) { rowptr[base + 1] = p; p += c1; }
  if (base + 2 < N) { rowptr[base + 2] = p; p += c2; }
  if (base + 3 < N) { rowptr[base + 3] = p; }
}

__global__ void scan_top_kernel(int* __restrict__ blocksum, int nb) {
  __shared__ int sd[256];
  const int t = threadIdx.x;
  const int chunk = (nb + 255) / 256;
  int lo = t * chunk, hi = lo + chunk;
  if (lo > nb) lo = nb;
  if (hi > nb) hi = nb;
  int s = 0;
  for (int i = lo; i < hi; ++i) s += blocksum[i];
  sd[t] = s;
  __syncthreads();
  for (int d = 1; d < 256; d <<= 1) {
    int v = (t >= d) ? sd[t - d] : 0;
    __syncthreads();
    sd[t] += v;
    __syncthreads();
  }
  int run = sd[t] - s;
  for (int i = lo; i < hi; ++i) { int v = blocksum[i]; blocksum[i] = run; run += v; }
}

__global__ void scan_add_kernel(int* __restrict__ rowptr, const int* __restrict__ blocksum,
                                int N, int E) {
  const int off = blocksum[blockIdx.x];
  const int base = blockIdx.x * 1024 + threadIdx.x * 4;
#pragma unroll
  for (int k = 0; k < 4; ++k)
    if (base + k < N) rowptr[base + k] += off;
  if (blockIdx.x == 0 && threadIdx.x == 0) rowptr[N] = E;
}

// CSR fill, no atomics: slot precomputed as rowptr[dst] + pos
__global__ void fill_kernel(const int* __restrict__ src, const int* __restrict__ dst,
                            const float* __restrict__ w, const float* __restrict__ deg,
                            const int* __restrict__ rowptr, const int* __restrict__ pos,
                            int2* __restrict__ epk, int E) {
  int e = blockIdx.x * blockDim.x + threadIdx.x;
  if (e >= E) return;
  int d = dst[e], s = src[e];
  int idx = rowptr[d] + pos[e];
  int2 pk;
  pk.x = s;
  pk.y = __float_as_int(w[e] * rsqrtf(deg[s] * deg[d]));
  epk[idx] = pk;
}

// M[row,:] = X[row,:] @ W (+bias, leaky-relu); fp32 out; DOUT/4 threads/row
template <int DIN, int DOUT, bool BIASACT>
__global__ void gemm_kernel(const float* __restrict__ X, const float* __restrict__ W,
                            const float* __restrict__ bias, float* __restrict__ M, int N) {
  constexpr int SUBS = DOUT / 4;
  int gid = blockIdx.x * blockDim.x + threadIdx.x;
  int row = gid / SUBS, sub = gid % SUBS;
  if (row >= N) return;
  const float* xr = X + (size_t)row * DIN;
  const float4* W4 = (const float4*)W;
  float4 acc = make_float4(0.f, 0.f, 0.f, 0.f);
#pragma unroll
  for (int k = 0; k < DIN; ++k) {
    float xk = xr[k];
    float4 w4 = W4[k * SUBS + sub];
    acc.x += xk * w4.x; acc.y += xk * w4.y; acc.z += xk * w4.z; acc.w += xk * w4.w;
  }
  if (BIASACT) {
    float4 b4 = ((const float4*)bias)[sub];
    acc.x += b4.x; acc.y += b4.y; acc.z += b4.z; acc.w += b4.w;
    acc.x = (acc.x >= 0.f) ? acc.x : 0.01f * acc.x;
    acc.y = (acc.y >= 0.f) ? acc.y : 0.01f * acc.y;
    acc.z = (acc.z >= 0.f) ? acc.z : 0.01f * acc.z;
    acc.w = (acc.w >= 0.f) ? acc.w : 0.01f * acc.w;
  }
  ((float4*)M)[(size_t)row * SUBS + sub] = acc;
}

// M[row,:] = X[row,:] @ W packed to bf16 (2/u32, RNE); DOUT/4 threads/row
template <int DIN, int DOUT>
__global__ void gemm_bf16_kernel(const float* __restrict__ X, const float* __restrict__ W,
                                 uint2* __restrict__ M, int N) {
  constexpr int SUBS = DOUT / 4;
  int gid = blockIdx.x * blockDim.x + threadIdx.x;
  int row = gid / SUBS, sub = gid % SUBS;
  if (row >= N) return;
  const float* xr = X + (size_t)row * DIN;
  const float4* W4 = (const float4*)W;
  float4 acc = make_float4(0.f, 0.f, 0.f, 0.f);
#pragma unroll
  for (int k = 0; k < DIN; ++k) {
    float xk = xr[k];
    float4 w4 = W4[k * SUBS + sub];
    acc.x += xk * w4.x; acc.y += xk * w4.y; acc.z += xk * w4.z; acc.w += xk * w4.w;
  }
  uint2 pk;
  pk.x = pk_bf16(acc.x, acc.y);
  pk.y = pk_bf16(acc.z, acc.w);
  M[(size_t)row * SUBS + sub] = pk;
}

// fp32 gather (layer 0, 24-wide). Unroll-8: 8 independent epk->m chains.
template <int DOUT, bool BIAS, bool ACT>
__global__ void gather_kernel(const float* __restrict__ m, const int* __restrict__ rowptr,
                              const int2* __restrict__ epk, const float* __restrict__ bias,
                              float* __restrict__ out, int N) {
  constexpr int SUBS = DOUT / 4;
  int gid = blockIdx.x * blockDim.x + threadIdx.x;
  int row = gid / SUBS, sub = gid % SUBS;
  if (row >= N) return;
  const int lo = rowptr[row], hi = rowptr[row + 1];
  const float4* m4 = (const float4*)m;
  float4 a0 = make_float4(0.f, 0.f, 0.f, 0.f);
  float4 a1 = make_float4(0.f, 0.f, 0.f, 0.f);
  int e = lo;
  for (; e + 8 <= hi; e += 8) {
    int2 p[8];
    float4 v[8];
#pragma unroll
    for (int k = 0; k < 8; ++k) p[k] = epk[e + k];
#pragma unroll
    for (int k = 0; k < 8; ++k) v[k] = m4[(size_t)p[k].x * SUBS + sub];
#pragma unroll
    for (int k = 0; k < 8; ++k) {
      float w = __int_as_float(p[k].y);
      float4* a = (k & 1) ? &a1 : &a0;
      a->x += w * v[k].x; a->y += w * v[k].y; a->z += w * v[k].z; a->w += w * v[k].w;
    }
  }
  for (; e + 4 <= hi; e += 4) {
    int2 p0 = epk[e], p1 = epk[e + 1], p2 = epk[e + 2], p3 = epk[e + 3];
    float4 v0 = m4[(size_t)p0.x * SUBS + sub];
    float4 v1 = m4[(size_t)p1.x * SUBS + sub];
    float4 v2 = m4[(size_t)p2.x * SUBS + sub];
    float4 v3 = m4[(size_t)p3.x * SUBS + sub];
    float w0 = __int_as_float(p0.y), w1 = __int_as_float(p1.y);
    float w2 = __int_as_float(p2.y), w3 = __int_as_float(p3.y);
    a0.x += w0 * v0.x; a0.y += w0 * v0.y; a0.z += w0 * v0.z; a0.w += w0 * v0.w;
    a1.x += w1 * v1.x; a1.y += w1 * v1.y; a1.z += w1 * v1.z; a1.w += w1 * v1.w;
    a0.x += w2 * v2.x; a0.y += w2 * v2.y; a0.z += w2 * v2.z; a0.w += w2 * v2.w;
    a1.x += w3 * v3.x; a1.y += w3 * v3.y; a1.z += w3 * v3.z; a1.w += w3 * v3.w;
  }
  for (; e < hi; ++e) {
    int2 pk = epk[e];
    float w = __int_as_float(pk.y);
    float4 v = m4[(size_t)pk.x * SUBS + sub];
    a0.x += w * v.x; a0.y += w * v.y; a0.z += w * v.z; a0.w += w * v.w;
  }
  float4 acc = make_float4(a0.x + a1.x, a0.y + a1.y, a0.z + a1.z, a0.w + a1.w);
  if (BIAS) {
    float4 b4 = ((const float4*)bias)[sub];
    acc.x += b4.x; acc.y += b4.y; acc.z += b4.z; acc.w += b4.w;
  }
  if (ACT) {
    acc.x = (acc.x >= 0.f) ? acc.x : 0.01f * acc.x;
    acc.y = (acc.y >= 0.f) ? acc.y : 0.01f * acc.y;
    acc.z = (acc.z >= 0.f) ? acc.z : 0.01f * acc.z;
    acc.w = (acc.w >= 0.f) ? acc.w : 0.01f * acc.w;
  }
  ((float4*)out)[(size_t)row * SUBS + sub] = acc;
}

// bf16 gather: W features/row, 8 bf16 (one uint4 = 16B) per lane per edge.
// out fp32 (+bias, opt leaky-relu). Unroll-8: 8 independent epk->m chains.
template <int W, bool ACT>
__global__ void gather_bf16_kernel(const uint4* __restrict__ m, const int* __restrict__ rowptr,
                                   const int2* __restrict__ epk, const float* __restrict__ bias,
                                   float* __restrict__ out, int N) {
  constexpr int SUBS = W / 8;
  int gid = blockIdx.x * blockDim.x + threadIdx.x;
  int row = gid / SUBS, sub = gid % SUBS;
  if (row >= N) return;
  const int lo = rowptr[row], hi = rowptr[row + 1];
  float acc[8];
#pragma unroll
  for (int k = 0; k < 8; ++k) acc[k] = 0.0f;
  int e = lo;
  for (; e + 8 <= hi; e += 8) {
    int2 p[8];
    uint4 v[8];
#pragma unroll
    for (int k = 0; k < 8; ++k) p[k] = epk[e + k];
#pragma unroll
    for (int k = 0; k < 8; ++k) v[k] = m[(size_t)p[k].x * SUBS + sub];
#pragma unroll
    for (int k = 0; k < 8; ++k) fma8(acc, v[k], __int_as_float(p[k].y));
  }
  for (; e + 4 <= hi; e += 4) {
    int2 p0 = epk[e], p1 = epk[e + 1], p2 = epk[e + 2], p3 = epk[e + 3];
    uint4 v0 = m[(size_t)p0.x * SUBS + sub];
    uint4 v1 = m[(size_t)p1.x * SUBS + sub];
    uint4 v2 = m[(size_t)p2.x * SUBS + sub];
    uint4 v3 = m[(size_t)p3.x * SUBS + sub];
    fma8(acc, v0, __int_as_float(p0.y));
    fma8(acc, v1, __int_as_float(p1.y));
    fma8(acc, v2, __int_as_float(p2.y));
    fma8(acc, v3, __int_as_float(p3.y));
  }
  for (; e < hi; ++e) {
    int2 pk = epk[e];
    uint4 v = m[(size_t)pk.x * SUBS + sub];
    fma8(acc, v, __int_as_float(pk.y));
  }
#pragma unroll
  for (int k = 0; k < 8; ++k) acc[k] += bias[sub * 8 + k];
  if (ACT) {
#pragma unroll
    for (int k = 0; k < 8; ++k) acc[k] = (acc[k] >= 0.f) ? acc[k] : 0.01f * acc[k];
  }
  float4* o4 = (float4*)(out + (size_t)row * W + sub * 8);
  o4[0] = make_float4(acc[0], acc[1], acc[2], acc[3]);
  o4[1] = make_float4(acc[4], acc[5], acc[6], acc[7]);
}

extern "C" void kernel_launch(void* const* d_in, const int* in_sizes, int n_in,
                              void* d_out, int out_size, void* d_ws, size_t ws_size,
                              hipStream_t stream) {
  const float* feat = (const float*)d_in[0];
  const int* esrc   = (const int*)d_in[1];
  const int* edst   = (const int*)d_in[2];
  const float* ew   = (const float*)d_in[3];
  const float* W_ih = (const float*)d_in[4];
  const float* W_hh = (const float*)d_in[5];
  const float* b_ih = (const float*)d_in[6];
  const float* b_hh = (const float*)d_in[7];
  const float* W0   = (const float*)d_in[8];
  const float* b0   = (const float*)d_in[9];
  const float* W1   = (const float*)d_in[10];
  const float* b1   = (const float*)d_in[11];
  const float* W2   = (const float*)d_in[12];
  const float* b2   = (const float*)d_in[13];
  const int N = in_sizes[0] / 8;
  const int E = in_sizes[1];
  float* out = (float*)d_out;

  // workspace (floats): buf0[24N] | bufM[64N] | bufA[64N] | deg[N] | rowptr[N+2] | epk[2E]
  float* buf0 = (float*)d_ws;
  float* bufM = buf0 + (size_t)N * 24;
  float* bufA = bufM + (size_t)N * 64;
  float* deg  = bufA + (size_t)N * 64;
  int* rowptr = (int*)(deg + N);
  int2* epk   = (int2*)(rowptr + N + 2);
  // aliases (all in bufM, each dead before the next use):
  //   cnt[N]+pos[E] (through fill) -> agg24[24N] (through gemm0)
  //   -> bf16 message buffers (gemm1/gather1: 32N u32; gemm2/gather2: 16N u32)
  int* cnt      = (int*)bufM;
  int* pos      = cnt + N;
  float* agg24  = bufM;
  float* featn  = bufA;
  int* blocksum = (int*)(bufA + (size_t)N * 16);

  const int gN = (N + BLK - 1) / BLK;
  const int gE = (E + BLK - 1) / BLK;
  const int gN16 = ((size_t)N * 16 + BLK - 1) / BLK;  // SUBS=16 kernels
  const int gN8  = ((size_t)N * 8 + BLK - 1) / BLK;   // SUBS=8 kernels
  const int gN6  = ((size_t)N * 6 + BLK - 1) / BLK;   // 24-wide fp32 gather
  const int gN4  = ((size_t)N * 4 + BLK - 1) / BLK;   // 32-wide bf16 gather
  const int nb = (N + 1023) / 1024;
  const int lstmBlocks = gN16;                        // 16 threads/node
  const int edgeBlocks = (E + 1023) / 1024;           // 1024 edges/block
  const int nGa = (lstmBlocks + 3) / 4;
  const int nG = (nGa > edgeBlocks) ? nGa : edgeBlocks;

  prep_kernel<<<gN, BLK, 0, stream>>>(feat, featn, buf0, deg, cnt, N);
  lstm_edge_kernel<<<nG * 5, BLK, 0, stream>>>(featn, W_ih, W_hh, b_ih, b_hh, buf0, N,
                                               esrc, edst, ew, deg, cnt, pos, E);
  scan_block_kernel<<<nb, 256, 0, stream>>>(cnt, rowptr, blocksum, N);
  scan_top_kernel<<<1, 256, 0, stream>>>(blocksum, nb);
  scan_add_kernel<<<nb, 256, 0, stream>>>(rowptr, blocksum, N, E);
  fill_kernel<<<gE, BLK, 0, stream>>>(esrc, edst, ew, deg, rowptr, pos, epk, E);

  // layer 0 (fp32): aggregate-first (24-wide) then transform+bias+act
  gather_kernel<24, false, false><<<gN6, BLK, 0, stream>>>(buf0, rowptr, epk, nullptr, agg24, N);
  gemm_kernel<24, 64, true><<<gN16, BLK, 0, stream>>>(agg24, W0, b0, bufA, N);
  // layer 1 (bf16 messages): transform -> bf16, aggregate, +b1+act
  gemm_bf16_kernel<64, 64><<<gN16, BLK, 0, stream>>>(bufA, W1, (uint2*)bufM, N);
  gather_bf16_kernel<64, true><<<gN8, BLK, 0, stream>>>((const uint4*)bufM, rowptr, epk, b1, bufA, N);
  // layer 2 (bf16 messages): transform 64->32 -> bf16, aggregate, +b2
  gemm_bf16_kernel<64, 32><<<gN8, BLK, 0, stream>>>(bufA, W2, (uint2*)bufM, N);
  gather_bf16_kernel<32, false><<<gN4, BLK, 0, stream>>>((const uint4*)bufM, rowptr, epk, b2, out, N);
}